// Round 1
// baseline (2294.306 us; speedup 1.0000x reference)
//
#include <hip/hip_runtime.h>
#include <hip/hip_bf16.h>

// ---------------------------------------------------------------------------
// BotGraphSAGE round 4:
//  - f1a + gemm_np: double-buffered LDS staging (16-k chunks, T14 async-stage
//    split: issue next chunk's global loads BEFORE computing current chunk,
//    write to alternate buffer after, ONE barrier per chunk). Kills the
//    barrier-serialized load->compute latency stall (VALUBusy 18%, HBM 14%,
//    occ 31% => latency-bound).
//  - head2 fused into final gemm_np (ACT==3): leaky -> x W_o2 -> atomicAdd,
//    removes a 51 MB P2 round trip + one dispatch.
//  - CSR build / f1b / f1c / aggregations unchanged.
// ---------------------------------------------------------------------------

#define BK_SHIFT 8
#define BK_SIZE 256
#define SXS 260   // LDS row stride (floats): 260%32==4 -> 2-way (free) on both
                  // the scattered write and the k-major read pattern.

__global__ void hist_kernel(const int* __restrict__ dst, int* __restrict__ cnt, int E) {
    int e = blockIdx.x * 256 + threadIdx.x;
    if (e < E) atomicAdd(&cnt[dst[e]], 1);
}

// ---- multi-block exclusive scan over cnt[N] -> off[N+1], invc[N] ----
__global__ void scan_reduce_kernel(const int* __restrict__ cnt, int* __restrict__ bsum, int n) {
    int t = threadIdx.x;
    int i = blockIdx.x * 256 + t;
    int v = (i < n) ? cnt[i] : 0;
#pragma unroll
    for (int s = 32; s > 0; s >>= 1) v += __shfl_down(v, s, 64);
    __shared__ int ws[4];
    if ((t & 63) == 0) ws[t >> 6] = v;
    __syncthreads();
    if (t == 0) bsum[blockIdx.x] = ws[0] + ws[1] + ws[2] + ws[3];
}

__global__ void scan_mid_kernel(const int* __restrict__ bsum, int* __restrict__ bbase, int nb) {
    __shared__ int sd[256];
    __shared__ int carry;
    int t = threadIdx.x;
    if (t == 0) carry = 0;
    __syncthreads();
    for (int base = 0; base < nb; base += 256) {
        int v = (base + t < nb) ? bsum[base + t] : 0;
        sd[t] = v;
        __syncthreads();
        for (int d = 1; d < 256; d <<= 1) {
            int x = (t >= d) ? sd[t - d] : 0;
            __syncthreads();
            sd[t] += x;
            __syncthreads();
        }
        if (base + t < nb) bbase[base + t] = carry + sd[t] - v;
        __syncthreads();
        if (t == 0) carry += sd[255];
        __syncthreads();
    }
}

__global__ void scan_final_kernel(const int* __restrict__ cnt, const int* __restrict__ bbase,
                                  int* __restrict__ off, float* __restrict__ invc, int n) {
    __shared__ int sd[256];
    int t = threadIdx.x;
    int i = blockIdx.x * 256 + t;
    int v = (i < n) ? cnt[i] : 0;
    sd[t] = v;
    __syncthreads();
    for (int d = 1; d < 256; d <<= 1) {
        int x = (t >= d) ? sd[t - d] : 0;
        __syncthreads();
        sd[t] += x;
        __syncthreads();
    }
    if (i < n) {
        off[i + 1] = bbase[blockIdx.x] + sd[t];
        invc[i] = 1.0f / fmaxf((float)v, 1.0f);
    }
    if (i == 0) off[0] = 0;
}

__global__ void init_gcur_kernel(const int* __restrict__ off, int* __restrict__ gcur, int nb, int n) {
    int b = blockIdx.x * 256 + threadIdx.x;
    if (b < nb) gcur[b] = off[b * BK_SIZE];
}

// ---- phase A: bin edges into buckets of BK_SIZE dst nodes ----
__global__ __launch_bounds__(256) void bucketA_kernel(const int* __restrict__ src,
    const int* __restrict__ dst, int* __restrict__ gcur,
    uint2* __restrict__ pairs, int E, int nb)
{
    __shared__ int lcnt[256];
    __shared__ int lbase[256];
    int t = threadIdx.x;
    int cbase = blockIdx.x * 4096;
    lcnt[t] = 0;
    __syncthreads();
#pragma unroll
    for (int r = 0; r < 16; ++r) {
        int e = cbase + r * 256 + t;
        if (e < E) atomicAdd(&lcnt[dst[e] >> BK_SHIFT], 1);
    }
    __syncthreads();
    if (t < nb && lcnt[t] > 0) lbase[t] = atomicAdd(&gcur[t], lcnt[t]);
    lcnt[t] = 0;
    __syncthreads();
#pragma unroll
    for (int r = 0; r < 16; ++r) {
        int e = cbase + r * 256 + t;
        if (e < E) {
            int d = dst[e];
            int bk = d >> BK_SHIFT;
            int pos = lbase[bk] + atomicAdd(&lcnt[bk], 1);
            pairs[pos] = make_uint2((unsigned)src[e], (unsigned)d);
        }
    }
}

// ---- phase B: per-bucket LDS-cursor final placement ----
__global__ __launch_bounds__(256) void bucketB_kernel(const uint2* __restrict__ pairs,
    const int* __restrict__ off, int* __restrict__ csr, int n)
{
    __shared__ int lcur[BK_SIZE];
    int t = threadIdx.x;
    int b = blockIdx.x;
    int d0 = b * BK_SIZE;
    int dlim = min(BK_SIZE, n - d0);
    if (t < dlim) lcur[t] = off[d0 + t];
    __syncthreads();
    int start = off[d0];
    int end = off[min(d0 + BK_SIZE, n)];
    for (int i = start + t; i < end; i += 256) {
        uint2 p = pairs[i];
        int pos = atomicAdd(&lcur[p.y & (BK_SIZE - 1)], 1);
        csr[pos] = (int)p.x;
    }
}

// ---------------------------------------------------------------------------
// f1a: des[N,768] @ W_des[768,32], split-K x4, node-per-lane.
// Double-buffered 16-k chunk pipeline: global loads for chunk ch+1 issue
// before the 512-FMA compute of chunk ch; LDS write + single barrier after.
// ---------------------------------------------------------------------------
__global__ __launch_bounds__(256) void f1a_kernel(const float* __restrict__ des,
    const float* __restrict__ W, float* __restrict__ part, int n)
{
    __shared__ float sX[2][16 * SXS];
    int t = threadIdx.x;
    int nbase = blockIdx.x * 256;
    int node = nbase + t;
    int kb0 = blockIdx.y * 192;
    int k4 = t & 3, nn0 = t >> 2;
    float acc[32];
#pragma unroll
    for (int c = 0; c < 32; ++c) acc[c] = 0.f;

    float4 stg[4];
#pragma unroll
    for (int r = 0; r < 4; ++r) {
        int gn = nbase + nn0 + r * 64;
        stg[r] = (gn < n) ? *reinterpret_cast<const float4*>(des + (size_t)gn * 768 + kb0 + k4 * 4)
                          : make_float4(0.f, 0.f, 0.f, 0.f);
    }
#pragma unroll
    for (int r = 0; r < 4; ++r) {
        int nn = nn0 + r * 64;
        sX[0][(k4 * 4 + 0) * SXS + nn] = stg[r].x;
        sX[0][(k4 * 4 + 1) * SXS + nn] = stg[r].y;
        sX[0][(k4 * 4 + 2) * SXS + nn] = stg[r].z;
        sX[0][(k4 * 4 + 3) * SXS + nn] = stg[r].w;
    }
    __syncthreads();

    for (int ch = 0; ch < 12; ++ch) {
        const float* cbuf = sX[ch & 1];
        float* nbuf = sX[(ch & 1) ^ 1];
        if (ch < 11) {
#pragma unroll
            for (int r = 0; r < 4; ++r) {
                int gn = nbase + nn0 + r * 64;
                stg[r] = (gn < n)
                    ? *reinterpret_cast<const float4*>(des + (size_t)gn * 768 + kb0 + (ch + 1) * 16 + k4 * 4)
                    : make_float4(0.f, 0.f, 0.f, 0.f);
            }
        }
        const float* wbase = W + (size_t)(kb0 + ch * 16) * 32;
#pragma unroll
        for (int k = 0; k < 16; ++k) {
            float x = cbuf[k * SXS + t];
            const float* wr = wbase + k * 32;   // wave-uniform -> s_load
#pragma unroll
            for (int c = 0; c < 32; ++c) acc[c] = fmaf(x, wr[c], acc[c]);
        }
        if (ch < 11) {
#pragma unroll
            for (int r = 0; r < 4; ++r) {
                int nn = nn0 + r * 64;
                nbuf[(k4 * 4 + 0) * SXS + nn] = stg[r].x;
                nbuf[(k4 * 4 + 1) * SXS + nn] = stg[r].y;
                nbuf[(k4 * 4 + 2) * SXS + nn] = stg[r].z;
                nbuf[(k4 * 4 + 3) * SXS + nn] = stg[r].w;
            }
            __syncthreads();
        }
    }
    if (node < n) {
        float* po = part + ((size_t)blockIdx.y * n + node) * 32;
#pragma unroll
        for (int c4 = 0; c4 < 8; ++c4)
            *reinterpret_cast<float4*>(po + c4 * 4) =
                make_float4(acc[c4 * 4], acc[c4 * 4 + 1], acc[c4 * 4 + 2], acc[c4 * 4 + 3]);
    }
}

__global__ void f1c_kernel(const float* __restrict__ part, const float* __restrict__ b,
                           float* __restrict__ Xout, int n) {
    int idx = blockIdx.x * 256 + threadIdx.x;
    if (idx >= n * 32) return;
    int node = idx >> 5, c = idx & 31;
    size_t stride = (size_t)n * 32;
    float v = part[idx] + part[stride + idx] + part[2 * stride + idx] + part[3 * stride + idx] + b[c];
    v = v > 0.f ? v : 0.01f * v;
    Xout[(size_t)node * 128 + c] = v;
}

__global__ __launch_bounds__(256) void f1b_kernel(const float* __restrict__ nump,
    const float* __restrict__ catp,
    const float* __restrict__ Wn, const float* __restrict__ bn,
    const float* __restrict__ Wc, const float* __restrict__ bc,
    float* __restrict__ Xout, int n)
{
    int idx = blockIdx.x * 256 + threadIdx.x;
    if (idx >= n * 84) return;
    int node = idx / 84;
    int c = idx - node * 84;
    float v;
    if (c < 42) {
        v = bn[c];
#pragma unroll
        for (int k = 0; k < 4; ++k) v += nump[node * 4 + k] * Wn[k * 42 + c];
    } else {
        int o = c - 42;
        v = bc[o];
#pragma unroll
        for (int k = 0; k < 3; ++k) v += catp[node * 3 + k] * Wc[k * 42 + o];
    }
    v = v > 0.f ? v : 0.01f * v;
    Xout[(size_t)node * 128 + 32 + c] = v;
}

// ---------------------------------------------------------------------------
// Node-per-lane GEMM, double-buffered 16-k chunk pipeline (see f1a).
// ACT: 0=none 1=relu 2=leaky 3=leaky + fused head (x W_o2 -> atomicAdd)
// ---------------------------------------------------------------------------
template<int K, int MODE, int ACT, int BIASM>
__global__ __launch_bounds__(256) void gemm_np_kernel(
    const float* __restrict__ X,
    const float* __restrict__ WA, const float* __restrict__ WB,
    const float* __restrict__ bias, const float* __restrict__ bias2,
    float* __restrict__ Y, int n)
{
    constexpr int NC = (K + 15) / 16;
    __shared__ float sX[2][16 * SXS];
    int t = threadIdx.x;
    int nbase = blockIdx.x * 256;
    int node = nbase + t;
    int cs = blockIdx.y;
    int k4 = t & 3, nn0 = t >> 2;
    float acc[32];
#pragma unroll
    for (int c = 0; c < 32; ++c) acc[c] = 0.f;

    float4 stg[4];
#pragma unroll
    for (int r = 0; r < 4; ++r) {
        int gn = nbase + nn0 + r * 64;
        stg[r] = (gn < n) ? *reinterpret_cast<const float4*>(X + (size_t)gn * 128 + k4 * 4)
                          : make_float4(0.f, 0.f, 0.f, 0.f);
    }
#pragma unroll
    for (int r = 0; r < 4; ++r) {
        int nn = nn0 + r * 64;
        sX[0][(k4 * 4 + 0) * SXS + nn] = stg[r].x;
        sX[0][(k4 * 4 + 1) * SXS + nn] = stg[r].y;
        sX[0][(k4 * 4 + 2) * SXS + nn] = stg[r].z;
        sX[0][(k4 * 4 + 3) * SXS + nn] = stg[r].w;
    }
    __syncthreads();

#pragma unroll
    for (int ch = 0; ch < NC; ++ch) {
        const float* cbuf = sX[ch & 1];
        float* nbuf = sX[(ch & 1) ^ 1];
        if (ch + 1 < NC) {
#pragma unroll
            for (int r = 0; r < 4; ++r) {
                int gn = nbase + nn0 + r * 64;
                stg[r] = (gn < n)
                    ? *reinterpret_cast<const float4*>(X + (size_t)gn * 128 + (ch + 1) * 16 + k4 * 4)
                    : make_float4(0.f, 0.f, 0.f, 0.f);
            }
        }
        constexpr int kb = 0;  // placeholder to keep structure clear
        (void)kb;
        const int kbase = ch * 16;
        const int klim = (K - kbase < 16) ? (K - kbase) : 16;
#pragma unroll
        for (int k = 0; k < 16; ++k) {
            if (k < klim) {
                float x = cbuf[k * SXS + t];
                int kk = kbase + k;
                const float* wr;
                if (MODE == 0)      wr = WA + (size_t)kk * 128 + cs * 32;
                else if (MODE == 1) wr = (cs < 2) ? (WA + (size_t)kk * 64 + cs * 32)
                                                  : (WB + (size_t)kk * 64 + (cs - 2) * 32);
                else                wr = (kk < 64) ? (WA + (size_t)kk * 128 + cs * 32)
                                                   : (WB + (size_t)(kk - 64) * 128 + cs * 32);
#pragma unroll
                for (int c = 0; c < 32; ++c) acc[c] = fmaf(x, wr[c], acc[c]);
            }
        }
        if (ch + 1 < NC) {
#pragma unroll
            for (int r = 0; r < 4; ++r) {
                int nn = nn0 + r * 64;
                nbuf[(k4 * 4 + 0) * SXS + nn] = stg[r].x;
                nbuf[(k4 * 4 + 1) * SXS + nn] = stg[r].y;
                nbuf[(k4 * 4 + 2) * SXS + nn] = stg[r].z;
                nbuf[(k4 * 4 + 3) * SXS + nn] = stg[r].w;
            }
            __syncthreads();
        }
    }

    if (node >= n) return;
    int c0 = cs * 32;

    if (ACT == 3) {
        // fused head: leaky(acc + b_o1) @ W_o2[128,2] partial -> atomicAdd
        float o0 = (cs == 0) ? bias2[0] : 0.f;
        float o1 = (cs == 0) ? bias2[1] : 0.f;
#pragma unroll
        for (int c = 0; c < 32; ++c) {
            float v = acc[c] + bias[c0 + c];
            v = v > 0.f ? v : 0.01f * v;
            o0 = fmaf(v, WB[(c0 + c) * 2],     o0);
            o1 = fmaf(v, WB[(c0 + c) * 2 + 1], o1);
        }
        atomicAdd(&Y[(size_t)node * 2],     o0);
        atomicAdd(&Y[(size_t)node * 2 + 1], o1);
        return;
    }

    float* yp = Y + (size_t)node * 128 + c0;
#pragma unroll
    for (int c = 0; c < 32; ++c) {
        float v = acc[c];
        if (BIASM == 1) v += bias[c0 + c];
        if (BIASM == 2) { if (cs >= 2) v += bias[c0 - 64 + c]; }
        if (ACT == 1) v = fmaxf(v, 0.f);
        else if (ACT == 2) v = v > 0.f ? v : 0.01f * v;
        acc[c] = v;
    }
#pragma unroll
    for (int c4 = 0; c4 < 8; ++c4)
        *reinterpret_cast<float4*>(yp + c4 * 4) =
            make_float4(acc[c4 * 4], acc[c4 * 4 + 1], acc[c4 * 4 + 2], acc[c4 * 4 + 3]);
}

// SAGE layer-a epilogue: H[dst] = relu(mean_agg(Y[:,0:64]) + Y[dst,64:128])
__global__ __launch_bounds__(256) void agg_a_kernel(const float* __restrict__ Y,
    const int* __restrict__ off, const int* __restrict__ csr,
    const float* __restrict__ invc, float* __restrict__ H, int n)
{
    int wid = (blockIdx.x * 256 + threadIdx.x) >> 6;
    int f = threadIdx.x & 63;
    if (wid >= n) return;
    float root = Y[(size_t)wid * 128 + 64 + f];
    int b = off[wid], e = off[wid + 1];
    float acc = 0.f;
    for (; b + 8 <= e; b += 8) {
        int idx[8];
#pragma unroll
        for (int j = 0; j < 8; ++j) idx[j] = csr[b + j];
        float v[8];
#pragma unroll
        for (int j = 0; j < 8; ++j) v[j] = Y[(size_t)idx[j] * 128 + f];
#pragma unroll
        for (int j = 0; j < 8; ++j) acc += v[j];
    }
    for (; b + 2 <= e; b += 2) {
        int s0 = csr[b], s1 = csr[b + 1];
        acc += Y[(size_t)s0 * 128 + f] + Y[(size_t)s1 * 128 + f];
    }
    for (; b < e; ++b) acc += Y[(size_t)csr[b] * 128 + f];
    float v = acc * invc[wid] + root;
    H[(size_t)wid * 64 + f] = fmaxf(v, 0.f);
}

// SAGE layer-b pre-GEMM: Z[dst,0:64] = mean_agg(H), Z[dst,64:128] = H[dst]
__global__ __launch_bounds__(256) void agg_b_kernel(const float* __restrict__ H,
    const int* __restrict__ off, const int* __restrict__ csr,
    const float* __restrict__ invc, float* __restrict__ Z, int n)
{
    int wid = (blockIdx.x * 256 + threadIdx.x) >> 6;
    int f = threadIdx.x & 63;
    if (wid >= n) return;
    float root = H[(size_t)wid * 64 + f];
    int b = off[wid], e = off[wid + 1];
    float acc = 0.f;
    for (; b + 8 <= e; b += 8) {
        int idx[8];
#pragma unroll
        for (int j = 0; j < 8; ++j) idx[j] = csr[b + j];
        float v[8];
#pragma unroll
        for (int j = 0; j < 8; ++j) v[j] = H[(size_t)idx[j] * 64 + f];
#pragma unroll
        for (int j = 0; j < 8; ++j) acc += v[j];
    }
    for (; b + 2 <= e; b += 2) {
        int s0 = csr[b], s1 = csr[b + 1];
        acc += H[(size_t)s0 * 64 + f] + H[(size_t)s1 * 64 + f];
    }
    for (; b < e; ++b) acc += H[(size_t)csr[b] * 64 + f];
    Z[(size_t)wid * 128 + f] = acc * invc[wid];
    Z[(size_t)wid * 128 + 64 + f] = root;
}

extern "C" void kernel_launch(void* const* d_in, const int* in_sizes, int n_in,
                              void* d_out, int out_size, void* d_ws, size_t ws_size,
                              hipStream_t stream)
{
    const float* des   = (const float*)d_in[0];
    const float* nump  = (const float*)d_in[2];
    const float* catp  = (const float*)d_in[3];
    const int*   ei    = (const int*)d_in[4];
    const float* W_des = (const float*)d_in[5];  const float* b_des = (const float*)d_in[6];
    const float* W_num = (const float*)d_in[7];  const float* b_num = (const float*)d_in[8];
    const float* W_cat = (const float*)d_in[9];  const float* b_cat = (const float*)d_in[10];
    const float* W_in  = (const float*)d_in[11]; const float* b_in  = (const float*)d_in[12];
    const float* s1a_Wl = (const float*)d_in[13]; const float* s1a_bl = (const float*)d_in[14];
    const float* s1a_Wr = (const float*)d_in[15];
    const float* s1b_Wl = (const float*)d_in[16]; const float* s1b_bl = (const float*)d_in[17];
    const float* s1b_Wr = (const float*)d_in[18];
    const float* s2a_Wl = (const float*)d_in[19]; const float* s2a_bl = (const float*)d_in[20];
    const float* s2a_Wr = (const float*)d_in[21];
    const float* s2b_Wl = (const float*)d_in[22]; const float* s2b_bl = (const float*)d_in[23];
    const float* s2b_Wr = (const float*)d_in[24];
    const float* W_o1  = (const float*)d_in[25]; const float* b_o1 = (const float*)d_in[26];
    const float* W_o2  = (const float*)d_in[27]; const float* b_o2 = (const float*)d_in[28];
    float* out = (float*)d_out;

    int N = in_sizes[0] / 768;
    int E = in_sizes[4] / 2;
    const int* srcp = ei;
    const int* dstp = ei + E;
    int NB = (N + BK_SIZE - 1) >> BK_SHIFT;       // dst buckets
    int NBLK = (N + 255) / 256;                   // scan blocks

    float* P0 = (float*)d_ws;
    float* P1 = P0 + (size_t)128 * N;
    float* P2 = P1 + (size_t)128 * N;   // f1a partials / agg temp / pair buffer (E*8B <= 128N*4B)
    int* cnt   = (int*)(P2 + (size_t)128 * N);
    int* off   = cnt + N;
    float* invc = (float*)(off + (N + 1));
    int* csr   = (int*)(invc + N);
    int* bsum  = csr + E;
    int* bbase = bsum + NBLK;
    int* gcur  = bbase + NBLK;
    uint2* pairs = (uint2*)P2;

    // --- CSR build ---
    hipMemsetAsync(cnt, 0, (size_t)N * sizeof(int), stream);
    hipMemsetAsync(out, 0, (size_t)N * 2 * sizeof(float), stream);   // for fused head atomics
    hist_kernel<<<(E + 255) / 256, 256, 0, stream>>>(dstp, cnt, E);
    scan_reduce_kernel<<<NBLK, 256, 0, stream>>>(cnt, bsum, N);
    scan_mid_kernel<<<1, 256, 0, stream>>>(bsum, bbase, NBLK);
    scan_final_kernel<<<NBLK, 256, 0, stream>>>(cnt, bbase, off, invc, N);
    init_gcur_kernel<<<(NB + 255) / 256, 256, 0, stream>>>(off, gcur, NB, N);
    bucketA_kernel<<<(E + 4095) / 4096, 256, 0, stream>>>(srcp, dstp, gcur, pairs, E, NB);
    bucketB_kernel<<<NB, 256, 0, stream>>>(pairs, off, csr, N);

    int nbn = (N + 255) / 256;
    dim3 gemm_grid(nbn, 4);
    int nbw = (N + 3) / 4;

    // --- Front MLP ---
    f1a_kernel<<<dim3(nbn, 4), 256, 0, stream>>>(des, W_des, P2, N);
    f1b_kernel<<<(N * 84 + 255) / 256, 256, 0, stream>>>(nump, catp, W_num, b_num, W_cat, b_cat, P0, N);
    f1c_kernel<<<(N * 32 + 255) / 256, 256, 0, stream>>>(P2, b_des, P0, N);
    gemm_np_kernel<116, 0, 2, 1><<<gemm_grid, 256, 0, stream>>>(P0, W_in, nullptr, b_in, nullptr, P1, N);

    // --- SAGE block 1 ---
    gemm_np_kernel<128, 1, 0, 2><<<gemm_grid, 256, 0, stream>>>(P1, s1a_Wl, s1a_Wr, s1a_bl, nullptr, P0, N);
    agg_a_kernel<<<nbw, 256, 0, stream>>>(P0, off, csr, invc, P2, N);
    agg_b_kernel<<<nbw, 256, 0, stream>>>(P2, off, csr, invc, P1, N);
    gemm_np_kernel<128, 2, 1, 1><<<gemm_grid, 256, 0, stream>>>(P1, s1b_Wl, s1b_Wr, s1b_bl, nullptr, P0, N);

    // --- SAGE block 2 ---
    gemm_np_kernel<128, 1, 0, 2><<<gemm_grid, 256, 0, stream>>>(P0, s2a_Wl, s2a_Wr, s2a_bl, nullptr, P1, N);
    agg_a_kernel<<<nbw, 256, 0, stream>>>(P1, off, csr, invc, P2, N);
    agg_b_kernel<<<nbw, 256, 0, stream>>>(P2, off, csr, invc, P0, N);
    gemm_np_kernel<128, 2, 1, 1><<<gemm_grid, 256, 0, stream>>>(P0, s2b_Wl, s2b_Wr, s2b_bl, nullptr, P1, N);

    // --- Head (W_o1 GEMM with fused leaky + W_o2 + b_o2 via atomics) ---
    gemm_np_kernel<128, 0, 3, 1><<<gemm_grid, 256, 0, stream>>>(P1, W_o1, W_o2, b_o1, b_o2, out, N);
}

// Round 2
// 922.477 us; speedup vs baseline: 2.4871x; 2.4871x over previous
//
#include <hip/hip_runtime.h>
#include <hip/hip_bf16.h>

// ---------------------------------------------------------------------------
// BotGraphSAGE round 5:
//  - REVERT round-4 manual double-buffering (compiler sank the prefetch loads,
//    VGPR 156, occupancy 9.8% -> 3.4x regression).
//  - NEW: feature-major (transposed) tensor chain. Node-per-lane GEMMs reading
//    X^T[k][N] need NO LDS and NO barriers (coalesced scalar loads). Tensors
//    feeding edge-gather aggs stay node-major. Layout chain:
//      f1a/f1b/f1c -> X^T (P0) -> W_in gemm_t -> H1^T (P1) -> s1a gemm_t
//      -> Y [N,128] (P2) -> agg_a -> H (P0) -> agg_b -> Z [N,128] (P1)
//      -> s1b staged gemm -> X2^T (P2) -> s2a gemm_t -> Y2 (P0) -> aggs
//      -> Z2 (P0) -> s2b staged -> X3^T (P1) -> head gemm_t (fused W_o2) -> out
//  - s1b/s2b keep round-3 staged structure (2 barriers/chunk), now 8 column
//    splits x 16-k chunks (LDS 16.5 KB, stride 258) for 6 blocks/CU.
//  - f1a: round-3 body, split-K x8, transposed partials.
// ---------------------------------------------------------------------------

#define BK_SHIFT 8
#define BK_SIZE 256

__global__ void hist_kernel(const int* __restrict__ dst, int* __restrict__ cnt, int E) {
    int e = blockIdx.x * 256 + threadIdx.x;
    if (e < E) atomicAdd(&cnt[dst[e]], 1);
}

// ---- multi-block exclusive scan over cnt[N] -> off[N+1], invc[N] ----
__global__ void scan_reduce_kernel(const int* __restrict__ cnt, int* __restrict__ bsum, int n) {
    int t = threadIdx.x;
    int i = blockIdx.x * 256 + t;
    int v = (i < n) ? cnt[i] : 0;
#pragma unroll
    for (int s = 32; s > 0; s >>= 1) v += __shfl_down(v, s, 64);
    __shared__ int ws[4];
    if ((t & 63) == 0) ws[t >> 6] = v;
    __syncthreads();
    if (t == 0) bsum[blockIdx.x] = ws[0] + ws[1] + ws[2] + ws[3];
}

__global__ void scan_mid_kernel(const int* __restrict__ bsum, int* __restrict__ bbase, int nb) {
    __shared__ int sd[256];
    __shared__ int carry;
    int t = threadIdx.x;
    if (t == 0) carry = 0;
    __syncthreads();
    for (int base = 0; base < nb; base += 256) {
        int v = (base + t < nb) ? bsum[base + t] : 0;
        sd[t] = v;
        __syncthreads();
        for (int d = 1; d < 256; d <<= 1) {
            int x = (t >= d) ? sd[t - d] : 0;
            __syncthreads();
            sd[t] += x;
            __syncthreads();
        }
        if (base + t < nb) bbase[base + t] = carry + sd[t] - v;
        __syncthreads();
        if (t == 0) carry += sd[255];
        __syncthreads();
    }
}

__global__ void scan_final_kernel(const int* __restrict__ cnt, const int* __restrict__ bbase,
                                  int* __restrict__ off, float* __restrict__ invc, int n) {
    __shared__ int sd[256];
    int t = threadIdx.x;
    int i = blockIdx.x * 256 + t;
    int v = (i < n) ? cnt[i] : 0;
    sd[t] = v;
    __syncthreads();
    for (int d = 1; d < 256; d <<= 1) {
        int x = (t >= d) ? sd[t - d] : 0;
        __syncthreads();
        sd[t] += x;
        __syncthreads();
    }
    if (i < n) {
        off[i + 1] = bbase[blockIdx.x] + sd[t];
        invc[i] = 1.0f / fmaxf((float)v, 1.0f);
    }
    if (i == 0) off[0] = 0;
}

__global__ void init_gcur_kernel(const int* __restrict__ off, int* __restrict__ gcur, int nb, int n) {
    int b = blockIdx.x * 256 + threadIdx.x;
    if (b < nb) gcur[b] = off[b * BK_SIZE];
}

// ---- phase A: bin edges into buckets of BK_SIZE dst nodes ----
__global__ __launch_bounds__(256) void bucketA_kernel(const int* __restrict__ src,
    const int* __restrict__ dst, int* __restrict__ gcur,
    uint2* __restrict__ pairs, int E, int nb)
{
    __shared__ int lcnt[256];
    __shared__ int lbase[256];
    int t = threadIdx.x;
    int cbase = blockIdx.x * 4096;
    lcnt[t] = 0;
    __syncthreads();
#pragma unroll
    for (int r = 0; r < 16; ++r) {
        int e = cbase + r * 256 + t;
        if (e < E) atomicAdd(&lcnt[dst[e] >> BK_SHIFT], 1);
    }
    __syncthreads();
    if (t < nb && lcnt[t] > 0) lbase[t] = atomicAdd(&gcur[t], lcnt[t]);
    lcnt[t] = 0;
    __syncthreads();
#pragma unroll
    for (int r = 0; r < 16; ++r) {
        int e = cbase + r * 256 + t;
        if (e < E) {
            int d = dst[e];
            int bk = d >> BK_SHIFT;
            int pos = lbase[bk] + atomicAdd(&lcnt[bk], 1);
            pairs[pos] = make_uint2((unsigned)src[e], (unsigned)d);
        }
    }
}

// ---- phase B: per-bucket LDS-cursor final placement ----
__global__ __launch_bounds__(256) void bucketB_kernel(const uint2* __restrict__ pairs,
    const int* __restrict__ off, int* __restrict__ csr, int n)
{
    __shared__ int lcur[BK_SIZE];
    int t = threadIdx.x;
    int b = blockIdx.x;
    int d0 = b * BK_SIZE;
    int dlim = min(BK_SIZE, n - d0);
    if (t < dlim) lcur[t] = off[d0 + t];
    __syncthreads();
    int start = off[d0];
    int end = off[min(d0 + BK_SIZE, n)];
    for (int i = start + t; i < end; i += 256) {
        uint2 p = pairs[i];
        int pos = atomicAdd(&lcur[p.y & (BK_SIZE - 1)], 1);
        csr[pos] = (int)p.x;
    }
}

// ---------------------------------------------------------------------------
// f1a: des[N,768] @ W_des[768,32], split-K x8 (96 k each), node-per-lane,
// round-3 staged body (stage -> barrier -> FMA -> barrier).
// Partials written feature-major: part[(split*32+c)*N + node] (coalesced).
// ---------------------------------------------------------------------------
__global__ __launch_bounds__(256) void f1a_kernel(const float* __restrict__ des,
    const float* __restrict__ W, float* __restrict__ part, int n)
{
    __shared__ float sX[32 * 257];
    int t = threadIdx.x;
    int nbase = blockIdx.x * 256;
    int node = nbase + t;
    int kb0 = blockIdx.y * 96;
    float acc[32];
#pragma unroll
    for (int c = 0; c < 32; ++c) acc[c] = 0.f;

    for (int kc = 0; kc < 96; kc += 32) {
        __syncthreads();
#pragma unroll
        for (int r = 0; r < 8; ++r) {
            int i = r * 256 + t;
            int k4 = i & 7, nn = i >> 3;
            int gn = nbase + nn;
            float4 v = make_float4(0.f, 0.f, 0.f, 0.f);
            if (gn < n)
                v = *reinterpret_cast<const float4*>(des + (size_t)gn * 768 + kb0 + kc + k4 * 4);
            sX[(k4 * 4 + 0) * 257 + nn] = v.x;
            sX[(k4 * 4 + 1) * 257 + nn] = v.y;
            sX[(k4 * 4 + 2) * 257 + nn] = v.z;
            sX[(k4 * 4 + 3) * 257 + nn] = v.w;
        }
        __syncthreads();
        const float* wbase = W + (size_t)(kb0 + kc) * 32;
#pragma unroll 4
        for (int k = 0; k < 32; ++k) {
            float x = sX[k * 257 + t];
            const float* wr = wbase + k * 32;   // wave-uniform -> s_load
#pragma unroll
            for (int c = 0; c < 32; ++c) acc[c] = fmaf(x, wr[c], acc[c]);
        }
    }
    if (node < n) {
        float* po = part + (size_t)(blockIdx.y * 32) * n + node;
#pragma unroll
        for (int c = 0; c < 32; ++c) po[(size_t)c * n] = acc[c];   // coalesced
    }
}

// f1c: sum 8 transposed partial slabs + bias + leaky -> X^T rows 0..31 (P0)
__global__ __launch_bounds__(256) void f1c_kernel(const float* __restrict__ part,
    const float* __restrict__ b, float* __restrict__ XT, int n)
{
    int node = blockIdx.x * 256 + threadIdx.x;
    if (node >= n) return;
#pragma unroll 8
    for (int c = 0; c < 32; ++c) {
        float v = b[c];
#pragma unroll
        for (int s = 0; s < 8; ++s) v += part[(size_t)(s * 32 + c) * n + node];
        v = v > 0.f ? v : 0.01f * v;
        XT[(size_t)c * n + node] = v;
    }
}

// f1b: num/cat linears -> X^T rows 32..115 (feature-major, coalesced stores)
__global__ __launch_bounds__(256) void f1b_kernel(const float* __restrict__ nump,
    const float* __restrict__ catp,
    const float* __restrict__ Wn, const float* __restrict__ bn,
    const float* __restrict__ Wc, const float* __restrict__ bc,
    float* __restrict__ XT, int n)
{
    int node = blockIdx.x * 256 + threadIdx.x;
    if (node >= n) return;
    float4 nv = *reinterpret_cast<const float4*>(nump + (size_t)node * 4);
    float c0 = catp[(size_t)node * 3];
    float c1 = catp[(size_t)node * 3 + 1];
    float c2 = catp[(size_t)node * 3 + 2];
#pragma unroll 6
    for (int c = 0; c < 42; ++c) {
        float vn = bn[c] + nv.x * Wn[c] + nv.y * Wn[42 + c] + nv.z * Wn[84 + c] + nv.w * Wn[126 + c];
        vn = vn > 0.f ? vn : 0.01f * vn;
        XT[(size_t)(32 + c) * n + node] = vn;
        float vc = bc[c] + c0 * Wc[c] + c1 * Wc[42 + c] + c2 * Wc[84 + c];
        vc = vc > 0.f ? vc : 0.01f * vc;
        XT[(size_t)(74 + c) * n + node] = vc;
    }
}

// ---------------------------------------------------------------------------
// gemm_t: transposed-input node-per-lane GEMM. X is feature-major [K][N]:
// lane load X[k*N+node] is perfectly coalesced -> NO LDS, NO barriers.
// 8 column splits of 16 (grid (nbn,8)).
// MODE 0: WA[K][128] cols cs*16.  MODE 1: cs<4 -> WA[K][64], else WB[K][64].
// ACT: 0 none, 1 relu, 2 leaky.  BIASM: 1 full bias[c0+c]; 2 only cs>=4.
// OUT: 0 transposed dword stores; 1 node-major float4; 3 fused head
//      (leaky(+bias) @ W_o2[128,2] -> atomicAdd, bias2 added by cs==0).
// ---------------------------------------------------------------------------
template<int K, int MODE, int ACT, int BIASM, int OUT>
__global__ __launch_bounds__(256) void gemm_t_kernel(
    const float* __restrict__ X,
    const float* __restrict__ WA, const float* __restrict__ WB,
    const float* __restrict__ bias, const float* __restrict__ bias2,
    float* __restrict__ Y, int n)
{
    int t = threadIdx.x;
    int node = blockIdx.x * 256 + t;
    if (node >= n) return;                     // no barriers -> safe
    int cs = blockIdx.y;
    int c0 = cs * 16;
    float acc[16];
#pragma unroll
    for (int c = 0; c < 16; ++c) acc[c] = 0.f;

    const float* xp = X + node;
    const float* wr0;
    if (MODE == 0)      wr0 = WA + c0;
    else                wr0 = (cs < 4) ? (WA + c0) : (WB + (c0 - 64));
    const int wstride = (MODE == 0) ? 128 : 64;

#pragma unroll 8
    for (int k = 0; k < K; ++k) {
        float x = xp[(size_t)k * n];           // coalesced dword load
        const float* wr = wr0 + (size_t)k * wstride;  // wave-uniform -> s_load
#pragma unroll
        for (int c = 0; c < 16; ++c) acc[c] = fmaf(x, wr[c], acc[c]);
    }

    if (OUT == 3) {
        // fused head: leaky(acc + b_o1) @ W_o2[128,2] partial -> atomicAdd
        float o0 = (cs == 0) ? bias2[0] : 0.f;
        float o1 = (cs == 0) ? bias2[1] : 0.f;
#pragma unroll
        for (int c = 0; c < 16; ++c) {
            float v = acc[c] + bias[c0 + c];
            v = v > 0.f ? v : 0.01f * v;
            o0 = fmaf(v, WB[(c0 + c) * 2],     o0);
            o1 = fmaf(v, WB[(c0 + c) * 2 + 1], o1);
        }
        atomicAdd(&Y[(size_t)node * 2],     o0);
        atomicAdd(&Y[(size_t)node * 2 + 1], o1);
        return;
    }

#pragma unroll
    for (int c = 0; c < 16; ++c) {
        float v = acc[c];
        if (BIASM == 1) v += bias[c0 + c];
        if (BIASM == 2) { if (cs >= 4) v += bias[c0 - 64 + c]; }
        if (ACT == 1) v = fmaxf(v, 0.f);
        else if (ACT == 2) v = v > 0.f ? v : 0.01f * v;
        acc[c] = v;
    }
    if (OUT == 0) {
#pragma unroll
        for (int c = 0; c < 16; ++c)
            Y[(size_t)(c0 + c) * n + node] = acc[c];   // coalesced
    } else {
        float* yp = Y + (size_t)node * 128 + c0;
#pragma unroll
        for (int c4 = 0; c4 < 4; ++c4)
            *reinterpret_cast<float4*>(yp + c4 * 4) =
                make_float4(acc[c4 * 4], acc[c4 * 4 + 1], acc[c4 * 4 + 2], acc[c4 * 4 + 3]);
    }
}

// ---------------------------------------------------------------------------
// gemm_sage_b: node-major input [N,128] (from agg_b), staged round-3 style.
// K=128 split 64/64 across WA[64][128]/WB[64][128]. 8 column splits of 16,
// 16-k chunks (LDS 16.5 KB, stride 258 -> 2-way free banks).
// Output: relu(acc + bias), feature-major stores (coalesced).
// ---------------------------------------------------------------------------
__global__ __launch_bounds__(256) void gemm_sage_b_kernel(
    const float* __restrict__ X,
    const float* __restrict__ WA, const float* __restrict__ WB,
    const float* __restrict__ bias,
    float* __restrict__ Y, int n)
{
    __shared__ float sX[16 * 258];
    int t = threadIdx.x;
    int nbase = blockIdx.x * 256;
    int node = nbase + t;
    int cs = blockIdx.y;
    int c0 = cs * 16;
    float acc[16];
#pragma unroll
    for (int c = 0; c < 16; ++c) acc[c] = 0.f;

    for (int ch = 0; ch < 8; ++ch) {
        int kb = ch * 16;
        __syncthreads();
#pragma unroll
        for (int r = 0; r < 4; ++r) {
            int i = r * 256 + t;
            int k4 = i & 3, nn = i >> 2;
            int gn = nbase + nn;
            float4 v = make_float4(0.f, 0.f, 0.f, 0.f);
            if (gn < n)
                v = *reinterpret_cast<const float4*>(X + (size_t)gn * 128 + kb + k4 * 4);
            sX[(k4 * 4 + 0) * 258 + nn] = v.x;
            sX[(k4 * 4 + 1) * 258 + nn] = v.y;
            sX[(k4 * 4 + 2) * 258 + nn] = v.z;
            sX[(k4 * 4 + 3) * 258 + nn] = v.w;
        }
        __syncthreads();
#pragma unroll 4
        for (int k = 0; k < 16; ++k) {
            float x = sX[k * 258 + t];
            int kk = kb + k;
            const float* wr = (kk < 64) ? (WA + (size_t)kk * 128 + c0)
                                        : (WB + (size_t)(kk - 64) * 128 + c0);
#pragma unroll
            for (int c = 0; c < 16; ++c) acc[c] = fmaf(x, wr[c], acc[c]);
        }
    }

    if (node >= n) return;
#pragma unroll
    for (int c = 0; c < 16; ++c) {
        float v = fmaxf(acc[c] + bias[c0 + c], 0.f);
        Y[(size_t)(c0 + c) * n + node] = v;    // coalesced feature-major
    }
}

// SAGE layer-a epilogue: H[dst] = relu(mean_agg(Y[:,0:64]) + Y[dst,64:128])
__global__ __launch_bounds__(256) void agg_a_kernel(const float* __restrict__ Y,
    const int* __restrict__ off, const int* __restrict__ csr,
    const float* __restrict__ invc, float* __restrict__ H, int n)
{
    int wid = (blockIdx.x * 256 + threadIdx.x) >> 6;
    int f = threadIdx.x & 63;
    if (wid >= n) return;
    float root = Y[(size_t)wid * 128 + 64 + f];
    int b = off[wid], e = off[wid + 1];
    float acc = 0.f;
    for (; b + 8 <= e; b += 8) {
        int idx[8];
#pragma unroll
        for (int j = 0; j < 8; ++j) idx[j] = csr[b + j];
        float v[8];
#pragma unroll
        for (int j = 0; j < 8; ++j) v[j] = Y[(size_t)idx[j] * 128 + f];
#pragma unroll
        for (int j = 0; j < 8; ++j) acc += v[j];
    }
    for (; b + 2 <= e; b += 2) {
        int s0 = csr[b], s1 = csr[b + 1];
        acc += Y[(size_t)s0 * 128 + f] + Y[(size_t)s1 * 128 + f];
    }
    for (; b < e; ++b) acc += Y[(size_t)csr[b] * 128 + f];
    float v = acc * invc[wid] + root;
    H[(size_t)wid * 64 + f] = fmaxf(v, 0.f);
}

// SAGE layer-b pre-GEMM: Z[dst,0:64] = mean_agg(H), Z[dst,64:128] = H[dst]
__global__ __launch_bounds__(256) void agg_b_kernel(const float* __restrict__ H,
    const int* __restrict__ off, const int* __restrict__ csr,
    const float* __restrict__ invc, float* __restrict__ Z, int n)
{
    int wid = (blockIdx.x * 256 + threadIdx.x) >> 6;
    int f = threadIdx.x & 63;
    if (wid >= n) return;
    float root = H[(size_t)wid * 64 + f];
    int b = off[wid], e = off[wid + 1];
    float acc = 0.f;
    for (; b + 8 <= e; b += 8) {
        int idx[8];
#pragma unroll
        for (int j = 0; j < 8; ++j) idx[j] = csr[b + j];
        float v[8];
#pragma unroll
        for (int j = 0; j < 8; ++j) v[j] = H[(size_t)idx[j] * 64 + f];
#pragma unroll
        for (int j = 0; j < 8; ++j) acc += v[j];
    }
    for (; b + 2 <= e; b += 2) {
        int s0 = csr[b], s1 = csr[b + 1];
        acc += H[(size_t)s0 * 64 + f] + H[(size_t)s1 * 64 + f];
    }
    for (; b < e; ++b) acc += H[(size_t)csr[b] * 64 + f];
    Z[(size_t)wid * 128 + f] = acc * invc[wid];
    Z[(size_t)wid * 128 + 64 + f] = root;
}

extern "C" void kernel_launch(void* const* d_in, const int* in_sizes, int n_in,
                              void* d_out, int out_size, void* d_ws, size_t ws_size,
                              hipStream_t stream)
{
    const float* des   = (const float*)d_in[0];
    const float* nump  = (const float*)d_in[2];
    const float* catp  = (const float*)d_in[3];
    const int*   ei    = (const int*)d_in[4];
    const float* W_des = (const float*)d_in[5];  const float* b_des = (const float*)d_in[6];
    const float* W_num = (const float*)d_in[7];  const float* b_num = (const float*)d_in[8];
    const float* W_cat = (const float*)d_in[9];  const float* b_cat = (const float*)d_in[10];
    const float* W_in  = (const float*)d_in[11]; const float* b_in  = (const float*)d_in[12];
    const float* s1a_Wl = (const float*)d_in[13]; const float* s1a_bl = (const float*)d_in[14];
    const float* s1a_Wr = (const float*)d_in[15];
    const float* s1b_Wl = (const float*)d_in[16]; const float* s1b_bl = (const float*)d_in[17];
    const float* s1b_Wr = (const float*)d_in[18];
    const float* s2a_Wl = (const float*)d_in[19]; const float* s2a_bl = (const float*)d_in[20];
    const float* s2a_Wr = (const float*)d_in[21];
    const float* s2b_Wl = (const float*)d_in[22]; const float* s2b_bl = (const float*)d_in[23];
    const float* s2b_Wr = (const float*)d_in[24];
    const float* W_o1  = (const float*)d_in[25]; const float* b_o1 = (const float*)d_in[26];
    const float* W_o2  = (const float*)d_in[27]; const float* b_o2 = (const float*)d_in[28];
    float* out = (float*)d_out;

    int N = in_sizes[0] / 768;
    int E = in_sizes[4] / 2;
    const int* srcp = ei;
    const int* dstp = ei + E;
    int NB = (N + BK_SIZE - 1) >> BK_SHIFT;       // dst buckets
    int NBLK = (N + 255) / 256;                   // scan blocks

    float* P0 = (float*)d_ws;
    float* P1 = P0 + (size_t)128 * N;
    float* P2 = P1 + (size_t)128 * N;   // pairs during CSR; f1a partials span P1..P2
    int* cnt   = (int*)(P2 + (size_t)128 * N);
    int* off   = cnt + N;
    float* invc = (float*)(off + (N + 1));
    int* csr   = (int*)(invc + N);
    int* bsum  = csr + E;
    int* bbase = bsum + NBLK;
    int* gcur  = bbase + NBLK;
    uint2* pairs = (uint2*)P2;

    // --- CSR build ---
    hipMemsetAsync(cnt, 0, (size_t)N * sizeof(int), stream);
    hipMemsetAsync(out, 0, (size_t)N * 2 * sizeof(float), stream);  // fused-head atomics
    hist_kernel<<<(E + 255) / 256, 256, 0, stream>>>(dstp, cnt, E);
    scan_reduce_kernel<<<NBLK, 256, 0, stream>>>(cnt, bsum, N);
    scan_mid_kernel<<<1, 256, 0, stream>>>(bsum, bbase, NBLK);
    scan_final_kernel<<<NBLK, 256, 0, stream>>>(cnt, bbase, off, invc, N);
    init_gcur_kernel<<<(NB + 255) / 256, 256, 0, stream>>>(off, gcur, NB, N);
    bucketA_kernel<<<(E + 4095) / 4096, 256, 0, stream>>>(srcp, dstp, gcur, pairs, E, NB);
    bucketB_kernel<<<NB, 256, 0, stream>>>(pairs, off, csr, N);

    int nbn = (N + 255) / 256;
    dim3 g8(nbn, 8);
    int nbw = (N + 3) / 4;

    // --- Front MLP:  X^T in P0 (rows 0..115) ---
    f1a_kernel<<<g8, 256, 0, stream>>>(des, W_des, P1, N);           // partials P1..P2
    f1b_kernel<<<nbn, 256, 0, stream>>>(nump, catp, W_num, b_num, W_cat, b_cat, P0, N);
    f1c_kernel<<<nbn, 256, 0, stream>>>(P1, b_des, P0, N);
    gemm_t_kernel<116, 0, 2, 1, 0><<<g8, 256, 0, stream>>>(P0, W_in, nullptr, b_in, nullptr, P1, N);

    // --- SAGE block 1 ---
    gemm_t_kernel<128, 1, 0, 2, 1><<<g8, 256, 0, stream>>>(P1, s1a_Wl, s1a_Wr, s1a_bl, nullptr, P2, N);
    agg_a_kernel<<<nbw, 256, 0, stream>>>(P2, off, csr, invc, P0, N);
    agg_b_kernel<<<nbw, 256, 0, stream>>>(P0, off, csr, invc, P1, N);
    gemm_sage_b_kernel<<<g8, 256, 0, stream>>>(P1, s1b_Wl, s1b_Wr, s1b_bl, P2, N);

    // --- SAGE block 2 ---
    gemm_t_kernel<128, 1, 0, 2, 1><<<g8, 256, 0, stream>>>(P2, s2a_Wl, s2a_Wr, s2a_bl, nullptr, P0, N);
    agg_a_kernel<<<nbw, 256, 0, stream>>>(P0, off, csr, invc, P1, N);
    agg_b_kernel<<<nbw, 256, 0, stream>>>(P1, off, csr, invc, P0, N);
    gemm_sage_b_kernel<<<g8, 256, 0, stream>>>(P0, s2b_Wl, s2b_Wr, s2b_bl, P1, N);

    // --- Head: leaky(X3^T @ W_o1 + b_o1) @ W_o2 + b_o2 (fused, atomics) ---
    gemm_t_kernel<128, 0, 3, 1, 3><<<g8, 256, 0, stream>>>(P1, W_o1, W_o2, b_o1, b_o2, out, N);
}